// Round 6
// baseline (190.813 us; speedup 1.0000x reference)
//
#include <hip/hip_runtime.h>

constexpr int S = 4096, M = 512, E = 16, CC = 128;
constexpr int H1 = 500, H2 = 500, H3 = 2000;

// fused: select = x@Wr^T + noise; top2; sel0 output; per-block column partials; zero counters
__global__ void k_route(const float* __restrict__ x, const float* __restrict__ noise,
                        const float* __restrict__ Wr, int* __restrict__ i0, int* __restrict__ i1,
                        float* __restrict__ g0, float* __restrict__ g1,
                        float* __restrict__ sel0, float* __restrict__ selpart,
                        int* __restrict__ counters) {
  if (blockIdx.x == 0 && threadIdx.x == 0) { counters[0] = 0; counters[1] = 0; }
  int wid = threadIdx.x >> 6, lane = threadIdx.x & 63;
  int s = blockIdx.x * 4 + wid;
  const float* xr = x + (size_t)s * M;
  float xv[8];
#pragma unroll
  for (int c = 0; c < 8; ++c) xv[c] = xr[lane + 64 * c];
  float v[E];
#pragma unroll
  for (int e = 0; e < E; ++e) {
    const float* wr = Wr + (size_t)e * M;
    float acc = 0.f;
#pragma unroll
    for (int c = 0; c < 8; ++c) acc = fmaf(xv[c], wr[lane + 64 * c], acc);
#pragma unroll
    for (int off = 32; off; off >>= 1) acc += __shfl_xor(acc, off);
    v[e] = acc + noise[s * E + e];
  }
  int a0 = 0; float m0 = v[0];
#pragma unroll
  for (int e = 1; e < E; ++e) if (v[e] > m0) { m0 = v[e]; a0 = e; }
  int a1 = -1; float m1 = -3.4e38f;
#pragma unroll
  for (int e = 0; e < E; ++e) if (e != a0 && v[e] > m1) { m1 = v[e]; a1 = e; }
  __shared__ float vsh[4][16];
  if (lane < 16) vsh[wid][lane] = v[lane];
  if (lane == 0) { i0[s] = a0; i1[s] = a1; g0[s] = m0; g1[s] = m1; }
  if (lane < 16) {
    int e = lane;
    sel0[(size_t)s * 32 + e * 2 + 0] = (e == a0 && m0 != 0.f) ? 1.f : 0.f;
    sel0[(size_t)s * 32 + e * 2 + 1] = (e == a1 && m1 != 0.f) ? 1.f : 0.f;
  }
  __syncthreads();
  if (threadIdx.x < 16) {
    int e = threadIdx.x;
    selpart[blockIdx.x * 16 + e] = vsh[0][e] + vsh[1][e] + vsh[2][e] + vsh[3][e];
  }
}

// fused lists+gather+reduce: block=(ek,chunk); 8 groups of 128 threads scan 512-token segments
__global__ __launch_bounds__(1024) void k_gather(const float* __restrict__ x,
                        const int* __restrict__ i0, const int* __restrict__ i1,
                        const float* __restrict__ g0, const float* __restrict__ g1,
                        float* __restrict__ ei) {
  __shared__ int rsi[S];
  __shared__ float rsg[S];
  __shared__ float gacc[8][128];
  int b = blockIdx.x;                 // 128 = ek*4 + chunk
  int chunk = b & 3, ek = b >> 2;
  int k = ek & 1, e = ek >> 1;
  const int* route = k ? i1 : i0;
  const float* gg = k ? g1 : g0;
  int t = threadIdx.x;
  for (int i = t; i < S; i += 1024) { rsi[i] = route[i]; rsg[i] = gg[i]; }
  __syncthreads();
  int g = t >> 7, dl = t & 127;
  int d = chunk * 128 + dl;
  float acc = 0.f;
  int q0 = g * 512;
  for (int q = q0; q < q0 + 512; ++q) {
    if (rsi[q] == e && rsg[q] != 0.f) acc += x[(size_t)q * M + d];
  }
  gacc[g][dl] = acc;
  __syncthreads();
  if (t < 128) {
    float ssum = 0.f;
#pragma unroll
    for (int g2 = 0; g2 < 8; ++g2) ssum += gacc[g2][t];
    ei[ek * M + chunk * 128 + t] = ssum;
  }
}

// generic MLP layer: wave per (e,h) output neuron, both k rows at once
template <int DIN, int HOUT, bool RELU>
__global__ void k_layer(const float* __restrict__ in, const float* __restrict__ W,
                        const float* __restrict__ bias, float* __restrict__ out) {
  int w = (blockIdx.x * blockDim.x + threadIdx.x) >> 6;
  int lane = threadIdx.x & 63;
  if (w >= E * HOUT) return;
  int e = w / HOUT, h = w - e * HOUT;
  const float* wr = W + ((size_t)e * HOUT + h) * DIN;
  const float* in0 = in + (size_t)(e * 2 + 0) * DIN;
  const float* in1 = in + (size_t)(e * 2 + 1) * DIN;
  float a0 = 0.f, a1 = 0.f;
  for (int m = lane; m < DIN; m += 64) {
    float wv = wr[m];
    a0 += wv * in0[m];
    a1 += wv * in1[m];
  }
#pragma unroll
  for (int off = 32; off; off >>= 1) {
    a0 += __shfl_xor(a0, off);
    a1 += __shfl_xor(a1, off);
  }
  if (lane == 0) {
    float bb = bias[e * HOUT + h];
    float o0 = a0 + bb, o1 = a1 + bb;
    if (RELU) { o0 = fmaxf(o0, 0.f); o1 = fmaxf(o1, 0.f); }
    out[(size_t)(e * 2 + 0) * HOUT + h] = o0;
    out[(size_t)(e * 2 + 1) * HOUT + h] = o1;
  }
}

// layer-4 (H3->CC, no relu) + last-block gprep: Gram32, row scalars, bw/cl, balance
__global__ __launch_bounds__(256) void k_l4(const float* __restrict__ h3in,
                        const float* __restrict__ W4, const float* __restrict__ b4,
                        float* __restrict__ eo,
                        const int* __restrict__ idx1, const int* __restrict__ idx2,
                        const int* __restrict__ i0, const int* __restrict__ i1,
                        const float* __restrict__ g0, const float* __restrict__ g1,
                        const float* __restrict__ selpart,
                        float* __restrict__ G32, float* __restrict__ rowg,
                        float* __restrict__ rowa, int* __restrict__ rowe,
                        float* __restrict__ cl, float* __restrict__ outb,
                        int ns, int ncnt, int npad, int* __restrict__ counters) {
  int w = (blockIdx.x * 256 + threadIdx.x) >> 6;
  int lane = threadIdx.x & 63;
  {
    int e = w / CC, h = w - e * CC;
    const float* wr = W4 + ((size_t)e * CC + h) * H3;
    const float* in0 = h3in + (size_t)(e * 2 + 0) * H3;
    const float* in1 = h3in + (size_t)(e * 2 + 1) * H3;
    float a0 = 0.f, a1 = 0.f;
    for (int m = lane; m < H3; m += 64) {
      float wv = wr[m];
      a0 += wv * in0[m];
      a1 += wv * in1[m];
    }
#pragma unroll
    for (int off = 32; off; off >>= 1) {
      a0 += __shfl_xor(a0, off);
      a1 += __shfl_xor(a1, off);
    }
    if (lane == 0) {
      float bb = b4[e * CC + h];
      eo[(size_t)(e * 2 + 0) * CC + h] = a0 + bb;
      eo[(size_t)(e * 2 + 1) * CC + h] = a1 + bb;
    }
  }
  // ---- last-block election ----
  __shared__ int lastflag;
  __syncthreads();
  if (threadIdx.x == 0) {
    __threadfence();
    int old = atomicAdd(&counters[0], 1);
    lastflag = (old == (int)gridDim.x - 1) ? 1 : 0;
  }
  __syncthreads();
  if (!lastflag) return;
  __threadfence();

  // ---- gprep (single block, 256 threads, fixed-order => deterministic) ----
  __shared__ float u_s[256 * 33];   // union: eo tile (32x132) | prep scatter ws
  __shared__ float Gs[1024];
  __shared__ double red_d[256];
  __shared__ float wf[32];
  __shared__ float dpl[16];
  int t = threadIdx.x;

  // Gram of the 32 base rows
  for (int i = t; i < 32 * 128; i += 256) u_s[(i >> 7) * 132 + (i & 127)] = eo[i];
  __syncthreads();
  for (int p = t; p < 1024; p += 256) {
    int u = p >> 5, v = p & 31;
    float s = 0.f;
#pragma unroll 8
    for (int d2 = 0; d2 < 128; ++d2) s = fmaf(u_s[u * 132 + d2], u_s[v * 132 + d2], s);
    Gs[p] = s; G32[p] = s;
  }
  __syncthreads();

  // rows + prep accumulation (thread-local stride)
  for (int e2 = 0; e2 < 33; ++e2) u_s[t * 33 + e2] = 0.f;
  double asum = 0.0;
  for (int r = t; r < npad; r += 256) {
    float g = 0.f; int ek = 0;
    if (r < ns)        { int tk = idx1[r];      ek = i0[tk] * 2 + 0; g = g0[tk]; }
    else if (r < ncnt) { int tk = idx2[r - ns]; ek = i1[tk] * 2 + 1; g = g1[tk]; }
    rowg[r] = g; rowe[r] = ek;
    float a = g * g * Gs[ek * 32 + ek];
    rowa[r] = a;
    asum += (double)a;
    u_s[t * 33 + ek] += g;
  }
  red_d[t] = asum;
  __syncthreads();
  if (t < 32) {
    float sw = 0.f;
    for (int q = 0; q < 256; ++q) sw += u_s[q * 33 + t];
    wf[t] = sw;
  }
  for (int off = 128; off; off >>= 1) { if (t < off) red_d[t] += red_d[t + off]; __syncthreads(); }
  double asum_tot = red_d[0];
  __syncthreads();
  double part = 0.0;
  for (int i = t; i < 1024; i += 256)
    part += (double)wf[i >> 5] * (double)wf[i & 31] * (double)Gs[i];
  red_d[t] = part;
  __syncthreads();
  for (int off = 128; off; off >>= 1) { if (t < off) red_d[t] += red_d[t + off]; __syncthreads(); }
  if (t == 0) {
    double nn = (double)ncnt;
    double sumd2 = 2.0 * nn * asum_tot - 2.0 * red_d[0];
    double bw = sumd2 / (nn * nn - nn) / 4.0;
#pragma unroll
    for (int l = 0; l < 5; ++l) cl[l] = (float)(1.0 / (bw * (double)(1 << l)));
  }
  __syncthreads();

  // balance loss
  {
    int e2 = t & 15, r0 = t >> 4;
    double acc = 0.0;
    for (int b2 = r0; b2 < 1024; b2 += 16) acc += (double)selpart[b2 * 16 + e2];
    red_d[t] = acc;
    __syncthreads();
    for (int off = 128; off >= 16; off >>= 1) { if (t < off) red_d[t] += red_d[t + off]; __syncthreads(); }
    if (t < 16) dpl[t] = (float)(red_d[t] / (double)S);
    __syncthreads();
    double acc2 = 0.0;
    for (int s2 = t; s2 < S; s2 += 256) acc2 += 0.5 * ((double)dpl[i0[s2]] + (double)dpl[i1[s2]]);
    red_d[t] = acc2;
    __syncthreads();
    for (int off = 128; off; off >>= 1) { if (t < off) red_d[t] += red_d[t + off]; __syncthreads(); }
    if (t == 0) outb[0] = (float)(red_d[0] / 256.0);
  }
}

// tail: blocks [0,2048) = token output; blocks [2048, 2048+ntri) = mmd tiles; last mmd block = final
__global__ __launch_bounds__(256) void k_tail(const float* __restrict__ eo,
                      const int* __restrict__ i0, const int* __restrict__ i1,
                      const float* __restrict__ g0, const float* __restrict__ g1,
                      float* __restrict__ out,
                      const float* __restrict__ rowg, const float* __restrict__ rowa,
                      const int* __restrict__ rowe, const float* __restrict__ G32,
                      const float* __restrict__ cl, double* __restrict__ bsum,
                      float* __restrict__ out_dist,
                      int ns, int ncnt, int nt, int ntri, int* __restrict__ counters) {
  __shared__ float K2[32 * 33];
  __shared__ float gAs[136], aAs[136], gBs[136], aBs[136];
  __shared__ int eAs[136], eBs[136];
  __shared__ float rsum[256];
  __shared__ double redf[256];
  __shared__ int lastflag;
  int b = blockIdx.x, tid = threadIdx.x;
  if (b < 2048) {
    int idx = b * 256 + tid;
    int s = idx >> 7, d = idx & (CC - 1);
    out[idx] = g0[s] * eo[(i0[s] * 2 + 0) * CC + d] + g1[s] * eo[(i1[s] * 2 + 1) * CC + d];
    return;
  }
  int L = b - 2048;
  int bi = 0, rem = L;
  while (rem >= nt - bi) { rem -= nt - bi; ++bi; }
  int bj = bi + rem;
  const int ib = bi * 128, jb = bj * 128;

  float c = cl[4];
  for (int i = tid; i < 1024; i += 256) K2[(i >> 5) * 33 + (i & 31)] = 2.f * c * G32[i];
  if (tid < 128) {
    int p = (tid & 7) * 17 + (tid >> 3);
    gAs[p] = rowg[ib + tid]; aAs[p] = c * rowa[ib + tid]; eAs[p] = rowe[ib + tid] * 33;
    gBs[p] = rowg[jb + tid]; aBs[p] = c * rowa[jb + tid]; eBs[p] = rowe[jb + tid];
  }
  __syncthreads();

  int ti = tid & 15, tj = tid >> 4;
  float gi[8], Ai[8], sgi[8], gj[8], Aj[8], sgj[8];
  int ei[8], ej[8];
#pragma unroll
  for (int r = 0; r < 8; ++r) {
    int i = ti * 8 + r, p = r * 17 + ti;
    gi[r] = gAs[p]; Ai[r] = aAs[p]; ei[r] = eAs[p];
    int m = ib + i;
    sgi[r] = (m < ns) ? 1.f : (m < ncnt ? -1.f : 0.f);
    int j = tj * 8 + r, q = r * 17 + tj;
    gj[r] = gBs[q]; Aj[r] = aBs[q]; ej[r] = eBs[q];
    int nn2 = jb + j;
    sgj[r] = (nn2 < ns) ? 1.f : (nn2 < ncnt ? -1.f : 0.f);
  }

  float tsum = 0.f;
#pragma unroll
  for (int r = 0; r < 8; ++r) {
#pragma unroll
    for (int q = 0; q < 8; ++q) {
      float gg = gi[r] * gj[q];
      float arg = fmaf(K2[ei[r] + ej[q]], gg, -(Ai[r] + Aj[q]));
      float t = __expf(arg);
      float t2 = t * t;   float s5 = t + t2;
      float t4 = t2 * t2; s5 += t4;
      float t8 = t4 * t4; s5 += t8;
      float t16 = t8 * t8; s5 += t16;
      tsum = fmaf(sgi[r] * sgj[q], s5, tsum);
    }
  }
  rsum[tid] = tsum;
  __syncthreads();
  for (int off = 128; off; off >>= 1) {
    if (tid < off) rsum[tid] += rsum[tid + off];
    __syncthreads();
  }
  if (tid == 0) bsum[L] = (double)rsum[0] * ((bi == bj) ? 1.0 : 2.0);

  // last-mmd-block election -> final reduce (fixed order, deterministic)
  if (tid == 0) {
    __threadfence();
    int old = atomicAdd(&counters[1], 1);
    lastflag = (old == ntri - 1) ? 1 : 0;
  }
  __syncthreads();
  if (!lastflag) return;
  __threadfence();
  double acc = 0.0;
  for (int i = tid; i < ntri; i += 256) acc += bsum[i];
  redf[tid] = acc;
  __syncthreads();
  for (int off = 128; off; off >>= 1) { if (tid < off) redf[tid] += redf[tid + off]; __syncthreads(); }
  if (tid == 0) out_dist[0] = (float)(-redf[0] / ((double)ns * (double)ns));
}

extern "C" void kernel_launch(void* const* d_in, const int* in_sizes, int n_in,
                              void* d_out, int out_size, void* d_ws, size_t ws_size,
                              hipStream_t stream) {
  const float* x  = (const float*)d_in[0];
  const float* noise = (const float*)d_in[1];
  const float* Wr = (const float*)d_in[2];
  const float* W1 = (const float*)d_in[3];
  const float* b1 = (const float*)d_in[4];
  const float* W2 = (const float*)d_in[5];
  const float* b2 = (const float*)d_in[6];
  const float* W3 = (const float*)d_in[7];
  const float* b3 = (const float*)d_in[8];
  const float* W4 = (const float*)d_in[9];
  const float* b4 = (const float*)d_in[10];
  const int* idx1 = (const int*)d_in[11];
  const int* idx2 = (const int*)d_in[12];
  int ns = in_sizes[11];
  int n = 2 * ns;
  int npad = (n + 127) & ~127;
  int nt = npad / 128;
  int ntri = nt * (nt + 1) / 2;

  char* wp = (char*)d_ws;
  size_t off = 0;
  auto alloc = [&](size_t bytes) -> void* {
    void* p = wp + off;
    off += (bytes + 255) & ~(size_t)255;
    return p;
  };
  int*   i0  = (int*)alloc((size_t)S * 4);
  int*   i1  = (int*)alloc((size_t)S * 4);
  float* g0  = (float*)alloc((size_t)S * 4);
  float* g1  = (float*)alloc((size_t)S * 4);
  float* selpart = (float*)alloc((size_t)1024 * 16 * 4);
  float* ei  = (float*)alloc((size_t)E * 2 * M * 4);
  float* h1  = (float*)alloc((size_t)E * 2 * H1 * 4);
  float* h2  = (float*)alloc((size_t)E * 2 * H2 * 4);
  float* h3  = (float*)alloc((size_t)E * 2 * H3 * 4);
  float* eo  = (float*)alloc((size_t)E * 2 * CC * 4);
  float* G32 = (float*)alloc((size_t)1024 * 4);
  float* rowg = (float*)alloc((size_t)npad * 4);
  float* rowa = (float*)alloc((size_t)npad * 4);
  int*   rowe = (int*)alloc((size_t)npad * 4);
  float* cl  = (float*)alloc(8 * 4);
  double* bsum = (double*)alloc((size_t)ntri * 8);
  int* counters = (int*)alloc(256);
  (void)ws_size; (void)n_in; (void)out_size;

  float* out      = (float*)d_out;
  float* out_sel0 = out + (size_t)S * CC;
  float* out_bal  = out + (size_t)S * CC + (size_t)S * E * 2;
  float* out_dist = out_bal + 1;

  k_route<<<S / 4, 256, 0, stream>>>(x, noise, Wr, i0, i1, g0, g1, out_sel0, selpart, counters);
  k_gather<<<128, 1024, 0, stream>>>(x, i0, i1, g0, g1, ei);
  k_layer<M, H1, true><<<(E * H1 + 3) / 4, 256, 0, stream>>>(ei, W1, b1, h1);
  k_layer<H1, H2, true><<<(E * H2 + 3) / 4, 256, 0, stream>>>(h1, W2, b2, h2);
  k_layer<H2, H3, true><<<(E * H3 + 3) / 4, 256, 0, stream>>>(h2, W3, b3, h3);
  k_l4<<<(E * CC) / 4, 256, 0, stream>>>(h3, W4, b4, eo, idx1, idx2, i0, i1, g0, g1,
                                         selpart, G32, rowg, rowa, rowe, cl, out_bal,
                                         ns, n, npad, counters);
  k_tail<<<2048 + ntri, 256, 0, stream>>>(eo, i0, i1, g0, g1, out, rowg, rowa, rowe,
                                          G32, cl, bsum, out_dist, ns, n, nt, ntri, counters);
}

// Round 7
// 170.357 us; speedup vs baseline: 1.1201x; 1.1201x over previous
//
#include <hip/hip_runtime.h>

constexpr int S = 4096, M = 512, E = 16, CC = 128;
constexpr int H1 = 500, H2 = 500, H3 = 2000;

// fused: select = x@Wr^T + noise; top2; sel0 output; per-block column partials; zero counter
__global__ void k_route(const float* __restrict__ x, const float* __restrict__ noise,
                        const float* __restrict__ Wr, int* __restrict__ i0, int* __restrict__ i1,
                        float* __restrict__ g0, float* __restrict__ g1,
                        float* __restrict__ sel0, float* __restrict__ selpart,
                        int* __restrict__ counters) {
  if (blockIdx.x == 0 && threadIdx.x == 0) { counters[0] = 0; }
  int wid = threadIdx.x >> 6, lane = threadIdx.x & 63;
  int s = blockIdx.x * 4 + wid;
  const float* xr = x + (size_t)s * M;
  float xv[8];
#pragma unroll
  for (int c = 0; c < 8; ++c) xv[c] = xr[lane + 64 * c];
  float v[E];
#pragma unroll
  for (int e = 0; e < E; ++e) {
    const float* wr = Wr + (size_t)e * M;
    float acc = 0.f;
#pragma unroll
    for (int c = 0; c < 8; ++c) acc = fmaf(xv[c], wr[lane + 64 * c], acc);
#pragma unroll
    for (int off = 32; off; off >>= 1) acc += __shfl_xor(acc, off);
    v[e] = acc + noise[s * E + e];
  }
  int a0 = 0; float m0 = v[0];
#pragma unroll
  for (int e = 1; e < E; ++e) if (v[e] > m0) { m0 = v[e]; a0 = e; }
  int a1 = -1; float m1 = -3.4e38f;
#pragma unroll
  for (int e = 0; e < E; ++e) if (e != a0 && v[e] > m1) { m1 = v[e]; a1 = e; }
  __shared__ float vsh[4][16];
  if (lane < 16) vsh[wid][lane] = v[lane];
  if (lane == 0) { i0[s] = a0; i1[s] = a1; g0[s] = m0; g1[s] = m1; }
  if (lane < 16) {
    int e = lane;
    sel0[(size_t)s * 32 + e * 2 + 0] = (e == a0 && m0 != 0.f) ? 1.f : 0.f;
    sel0[(size_t)s * 32 + e * 2 + 1] = (e == a1 && m1 != 0.f) ? 1.f : 0.f;
  }
  __syncthreads();
  if (threadIdx.x < 16) {
    int e = threadIdx.x;
    selpart[blockIdx.x * 16 + e] = vsh[0][e] + vsh[1][e] + vsh[2][e] + vsh[3][e];
  }
}

// fused lists+gather+reduce: block=(ek,chunk); 8 groups of 128 threads scan 512-token segments
__global__ __launch_bounds__(1024) void k_gather(const float* __restrict__ x,
                        const int* __restrict__ i0, const int* __restrict__ i1,
                        const float* __restrict__ g0, const float* __restrict__ g1,
                        float* __restrict__ ei) {
  __shared__ int rsi[S];
  __shared__ float rsg[S];
  __shared__ float gacc[8][128];
  int b = blockIdx.x;                 // 128 = ek*4 + chunk
  int chunk = b & 3, ek = b >> 2;
  int k = ek & 1, e = ek >> 1;
  const int* route = k ? i1 : i0;
  const float* gg = k ? g1 : g0;
  int t = threadIdx.x;
  for (int i = t; i < S; i += 1024) { rsi[i] = route[i]; rsg[i] = gg[i]; }
  __syncthreads();
  int g = t >> 7, dl = t & 127;
  int d = chunk * 128 + dl;
  float acc = 0.f;
  int q0 = g * 512;
  for (int q = q0; q < q0 + 512; ++q) {
    if (rsi[q] == e && rsg[q] != 0.f) acc += x[(size_t)q * M + d];
  }
  gacc[g][dl] = acc;
  __syncthreads();
  if (t < 128) {
    float ssum = 0.f;
#pragma unroll
    for (int g2 = 0; g2 < 8; ++g2) ssum += gacc[g2][t];
    ei[ek * M + chunk * 128 + t] = ssum;
  }
}

// generic MLP layer: wave per (e,h) output neuron, both k rows at once
template <int DIN, int HOUT, bool RELU>
__global__ void k_layer(const float* __restrict__ in, const float* __restrict__ W,
                        const float* __restrict__ bias, float* __restrict__ out) {
  int w = (blockIdx.x * blockDim.x + threadIdx.x) >> 6;
  int lane = threadIdx.x & 63;
  if (w >= E * HOUT) return;
  int e = w / HOUT, h = w - e * HOUT;
  const float* wr = W + ((size_t)e * HOUT + h) * DIN;
  const float* in0 = in + (size_t)(e * 2 + 0) * DIN;
  const float* in1 = in + (size_t)(e * 2 + 1) * DIN;
  float a0 = 0.f, a1 = 0.f;
  for (int m = lane; m < DIN; m += 64) {
    float wv = wr[m];
    a0 += wv * in0[m];
    a1 += wv * in1[m];
  }
#pragma unroll
  for (int off = 32; off; off >>= 1) {
    a0 += __shfl_xor(a0, off);
    a1 += __shfl_xor(a1, off);
  }
  if (lane == 0) {
    float bb = bias[e * HOUT + h];
    float o0 = a0 + bb, o1 = a1 + bb;
    if (RELU) { o0 = fmaxf(o0, 0.f); o1 = fmaxf(o1, 0.f); }
    out[(size_t)(e * 2 + 0) * HOUT + h] = o0;
    out[(size_t)(e * 2 + 1) * HOUT + h] = o1;
  }
}

// gprep: block 0 = Gram32 + balance; blocks 1.. = row scalars + per-ek w/w2 partials
__global__ __launch_bounds__(256) void k_gprep(const float* __restrict__ eo,
                        const float* __restrict__ selpart,
                        const int* __restrict__ idx1, const int* __restrict__ idx2,
                        const int* __restrict__ i0, const int* __restrict__ i1,
                        const float* __restrict__ g0, const float* __restrict__ g1,
                        float* __restrict__ G32, float* __restrict__ rowg,
                        int* __restrict__ rowe, float* __restrict__ wpart,
                        float* __restrict__ outb, int ns, int ncnt, int npad) {
  int t = threadIdx.x;
  if (blockIdx.x == 0) {
    __shared__ float Es[32 * 132];
    __shared__ double red_d[256];
    __shared__ float dpl[16];
    for (int i = t; i < 32 * 128; i += 256) Es[(i >> 7) * 132 + (i & 127)] = eo[i];
    __syncthreads();
    for (int p = t; p < 1024; p += 256) {
      int u = p >> 5, v = p & 31;
      float s = 0.f;
#pragma unroll 8
      for (int d = 0; d < 128; ++d) s = fmaf(Es[u * 132 + d], Es[v * 132 + d], s);
      G32[p] = s;
    }
    // balance loss
    int e2 = t & 15, r0 = t >> 4;
    double acc = 0.0;
    for (int b2 = r0; b2 < 1024; b2 += 16) acc += (double)selpart[b2 * 16 + e2];
    red_d[t] = acc;
    __syncthreads();
    for (int off = 128; off >= 16; off >>= 1) { if (t < off) red_d[t] += red_d[t + off]; __syncthreads(); }
    if (t < 16) dpl[t] = (float)(red_d[t] / (double)S);
    __syncthreads();
    double acc2 = 0.0;
    for (int s2 = t; s2 < S; s2 += 256) acc2 += 0.5 * ((double)dpl[i0[s2]] + (double)dpl[i1[s2]]);
    red_d[t] = acc2;
    __syncthreads();
    for (int off = 128; off; off >>= 1) { if (t < off) red_d[t] += red_d[t + off]; __syncthreads(); }
    if (t == 0) outb[0] = (float)(red_d[0] / 256.0);
    return;
  }
  // rows blocks: 1 row per thread
  int blk = blockIdx.x - 1;
  int r = blk * 256 + t;
  float g = 0.f; int ek = 0;
  if (r < ns)        { int tk = idx1[r];      ek = i0[tk] * 2 + 0; g = g0[tk]; }
  else if (r < ncnt) { int tk = idx2[r - ns]; ek = i1[tk] * 2 + 1; g = g1[tk]; }
  if (r < npad) { rowg[r] = g; rowe[r] = ek; }
  __shared__ float sw[4][32], sw2[4][32];
  int lane = t & 63, w = t >> 6;
  float g2 = g * g;
  for (int e = 0; e < 32; ++e) {
    float vw = (ek == e) ? g : 0.f;
    float vw2 = (ek == e) ? g2 : 0.f;
#pragma unroll
    for (int off = 32; off; off >>= 1) { vw += __shfl_xor(vw, off); vw2 += __shfl_xor(vw2, off); }
    if (lane == 0) { sw[w][e] = vw; sw2[w][e] = vw2; }
  }
  __syncthreads();
  if (t < 32) {
    wpart[blk * 64 + t]      = sw[0][t] + sw[1][t] + sw[2][t] + sw[3][t];
    wpart[blk * 64 + 32 + t] = sw2[0][t] + sw2[1][t] + sw2[2][t] + sw2[3][t];
  }
}

// tail: blocks [0,ntri) = mmd tiles (with in-block cl recompute, fixed-order => deterministic);
//       blocks [ntri, ntri+2048) = token output; last mmd block = final reduce
__global__ __launch_bounds__(256) void k_tail(const float* __restrict__ eo,
                      const int* __restrict__ i0, const int* __restrict__ i1,
                      const float* __restrict__ g0, const float* __restrict__ g1,
                      float* __restrict__ out,
                      const float* __restrict__ rowg, const int* __restrict__ rowe,
                      const float* __restrict__ G32, const float* __restrict__ wpart,
                      double* __restrict__ bsum, float* __restrict__ out_dist,
                      int ns, int ncnt, int nt, int ntri, int nrowblk,
                      int* __restrict__ counters) {
  int b = blockIdx.x, tid = threadIdx.x;
  if (b >= ntri) {
    int idx = (b - ntri) * 256 + tid;
    int s = idx >> 7, d = idx & (CC - 1);
    out[idx] = g0[s] * eo[(i0[s] * 2 + 0) * CC + d] + g1[s] * eo[(i1[s] * 2 + 1) * CC + d];
    return;
  }
  __shared__ float K2[32 * 33];
  __shared__ float wf[32], w2f[32];
  __shared__ double redd[256];
  __shared__ float c_sh;
  __shared__ float gAs[136], aAs[136], gBs[136], aBs[136];
  __shared__ int eAs[136], eBs[136];
  __shared__ float rsum[256];
  __shared__ int lastflag;

  int L = b;
  int bi = 0, rem = L;
  while (rem >= nt - bi) { rem -= nt - bi; ++bi; }
  int bj = bi + rem;
  const int ib = bi * 128, jb = bj * 128;

  // --- recompute c = 1/(bw*16) from wpart + G32 (identical in every block) ---
  if (tid < 32) {
    float sw = 0.f, sw2 = 0.f;
    for (int b2 = 0; b2 < nrowblk; ++b2) { sw += wpart[b2 * 64 + tid]; sw2 += wpart[b2 * 64 + 32 + tid]; }
    wf[tid] = sw; w2f[tid] = sw2;
  }
  for (int i = tid; i < 1024; i += 256) K2[(i >> 5) * 33 + (i & 31)] = G32[i];
  __syncthreads();
  double part = 0.0;
  for (int i = tid; i < 1024; i += 256)
    part += (double)wf[i >> 5] * (double)wf[i & 31] * (double)K2[(i >> 5) * 33 + (i & 31)];
  redd[tid] = part;
  __syncthreads();
  for (int off = 128; off; off >>= 1) { if (tid < off) redd[tid] += redd[tid + off]; __syncthreads(); }
  double wGw = redd[0];
  __syncthreads();
  redd[tid] = (tid < 32) ? (double)w2f[tid] * (double)K2[tid * 34] : 0.0;
  __syncthreads();
  for (int off = 128; off; off >>= 1) { if (tid < off) redd[tid] += redd[tid + off]; __syncthreads(); }
  if (tid == 0) {
    double nn = (double)ncnt;
    double sumd2 = 2.0 * nn * redd[0] - 2.0 * wGw;
    double bw = sumd2 / (nn * nn - nn) / 4.0;
    c_sh = (float)(1.0 / (bw * 16.0));
  }
  __syncthreads();
  float c = c_sh;
  for (int i = tid; i < 1056; i += 256) K2[i] *= 2.f * c;
  __syncthreads();

  // --- stage row scalars (17-stride swizzle) ---
  if (tid < 128) {
    int p = (tid & 7) * 17 + (tid >> 3);
    float ga = rowg[ib + tid]; int ea = rowe[ib + tid];
    float gb = rowg[jb + tid]; int eb = rowe[jb + tid];
    gAs[p] = ga; aAs[p] = 0.5f * ga * ga * K2[ea * 34]; eAs[p] = ea * 33;
    gBs[p] = gb; aBs[p] = 0.5f * gb * gb * K2[eb * 34]; eBs[p] = eb;
  }
  __syncthreads();

  int ti = tid & 15, tj = tid >> 4;
  float gi[8], Ai[8], sgi[8], gj[8], Aj[8], sgj[8];
  int ei[8], ej[8];
#pragma unroll
  for (int r = 0; r < 8; ++r) {
    int i = ti * 8 + r, p = r * 17 + ti;
    gi[r] = gAs[p]; Ai[r] = aAs[p]; ei[r] = eAs[p];
    int m = ib + i;
    sgi[r] = (m < ns) ? 1.f : (m < ncnt ? -1.f : 0.f);
    int j = tj * 8 + r, q = r * 17 + tj;
    gj[r] = gBs[q]; Aj[r] = aBs[q]; ej[r] = eBs[q];
    int nn2 = jb + j;
    sgj[r] = (nn2 < ns) ? 1.f : (nn2 < ncnt ? -1.f : 0.f);
  }

  float tsum = 0.f;
#pragma unroll
  for (int r = 0; r < 8; ++r) {
#pragma unroll
    for (int q = 0; q < 8; ++q) {
      float gg = gi[r] * gj[q];
      float arg = fmaf(K2[ei[r] + ej[q]], gg, -(Ai[r] + Aj[q]));
      float t = __expf(arg);
      float t2 = t * t;   float s5 = t + t2;
      float t4 = t2 * t2; s5 += t4;
      float t8 = t4 * t4; s5 += t8;
      float t16 = t8 * t8; s5 += t16;
      tsum = fmaf(sgi[r] * sgj[q], s5, tsum);
    }
  }
  rsum[tid] = tsum;
  __syncthreads();
  for (int off = 128; off; off >>= 1) {
    if (tid < off) rsum[tid] += rsum[tid + off];
    __syncthreads();
  }
  if (tid == 0) bsum[L] = (double)rsum[0] * ((bi == bj) ? 1.0 : 2.0);

  // last-mmd-block election -> final reduce (fixed order, deterministic)
  if (tid == 0) {
    __threadfence();
    int old = atomicAdd(&counters[0], 1);
    lastflag = (old == ntri - 1) ? 1 : 0;
  }
  __syncthreads();
  if (!lastflag) return;
  __threadfence();
  double acc = 0.0;
  for (int i = tid; i < ntri; i += 256) acc += bsum[i];
  redd[tid] = acc;
  __syncthreads();
  for (int off = 128; off; off >>= 1) { if (tid < off) redd[tid] += redd[tid + off]; __syncthreads(); }
  if (tid == 0) out_dist[0] = (float)(-redd[0] / ((double)ns * (double)ns));
}

extern "C" void kernel_launch(void* const* d_in, const int* in_sizes, int n_in,
                              void* d_out, int out_size, void* d_ws, size_t ws_size,
                              hipStream_t stream) {
  const float* x  = (const float*)d_in[0];
  const float* noise = (const float*)d_in[1];
  const float* Wr = (const float*)d_in[2];
  const float* W1 = (const float*)d_in[3];
  const float* b1 = (const float*)d_in[4];
  const float* W2 = (const float*)d_in[5];
  const float* b2 = (const float*)d_in[6];
  const float* W3 = (const float*)d_in[7];
  const float* b3 = (const float*)d_in[8];
  const float* W4 = (const float*)d_in[9];
  const float* b4 = (const float*)d_in[10];
  const int* idx1 = (const int*)d_in[11];
  const int* idx2 = (const int*)d_in[12];
  int ns = in_sizes[11];
  int n = 2 * ns;
  int npad = (n + 127) & ~127;
  int nt = npad / 128;
  int ntri = nt * (nt + 1) / 2;
  int nrowblk = (npad + 255) / 256;

  char* wp = (char*)d_ws;
  size_t off = 0;
  auto alloc = [&](size_t bytes) -> void* {
    void* p = wp + off;
    off += (bytes + 255) & ~(size_t)255;
    return p;
  };
  int*   i0  = (int*)alloc((size_t)S * 4);
  int*   i1  = (int*)alloc((size_t)S * 4);
  float* g0  = (float*)alloc((size_t)S * 4);
  float* g1  = (float*)alloc((size_t)S * 4);
  float* selpart = (float*)alloc((size_t)1024 * 16 * 4);
  float* ei  = (float*)alloc((size_t)E * 2 * M * 4);
  float* h1  = (float*)alloc((size_t)E * 2 * H1 * 4);
  float* h2  = (float*)alloc((size_t)E * 2 * H2 * 4);
  float* h3  = (float*)alloc((size_t)E * 2 * H3 * 4);
  float* eo  = (float*)alloc((size_t)E * 2 * CC * 4);
  float* G32 = (float*)alloc((size_t)1024 * 4);
  float* rowg = (float*)alloc((size_t)npad * 4);
  int*   rowe = (int*)alloc((size_t)npad * 4);
  float* wpart = (float*)alloc((size_t)nrowblk * 64 * 4);
  double* bsum = (double*)alloc((size_t)ntri * 8);
  int* counters = (int*)alloc(256);
  (void)ws_size; (void)n_in; (void)out_size;

  float* out      = (float*)d_out;
  float* out_sel0 = out + (size_t)S * CC;
  float* out_bal  = out + (size_t)S * CC + (size_t)S * E * 2;
  float* out_dist = out_bal + 1;

  k_route<<<S / 4, 256, 0, stream>>>(x, noise, Wr, i0, i1, g0, g1, out_sel0, selpart, counters);
  k_gather<<<128, 1024, 0, stream>>>(x, i0, i1, g0, g1, ei);
  k_layer<M, H1, true><<<(E * H1 + 3) / 4, 256, 0, stream>>>(ei, W1, b1, h1);
  k_layer<H1, H2, true><<<(E * H2 + 3) / 4, 256, 0, stream>>>(h1, W2, b2, h2);
  k_layer<H2, H3, true><<<(E * H3 + 3) / 4, 256, 0, stream>>>(h2, W3, b3, h3);
  k_layer<H3, CC, false><<<(E * CC + 3) / 4, 256, 0, stream>>>(h3, W4, b4, eo);
  k_gprep<<<1 + nrowblk, 256, 0, stream>>>(eo, selpart, idx1, idx2, i0, i1, g0, g1,
                                           G32, rowg, rowe, wpart, out_bal, ns, n, npad);
  k_tail<<<ntri + 2048, 256, 0, stream>>>(eo, i0, i1, g0, g1, out, rowg, rowe, G32,
                                          wpart, bsum, out_dist, ns, n, nt, ntri,
                                          nrowblk, counters);
}